// Round 4
// baseline (688.766 us; speedup 1.0000x reference)
//
#include <hip/hip_runtime.h>
#include <math.h>

#define NZ 10
#define NLENS 29
#define NPAIR 45
#define NUNIT 23
#define UB 5
#define SSTR 1028               // padded wave-slice stride (float2)
#define PSTH 525312             // half-plane stride = 513*1024 (float2)

static __device__ __forceinline__ float2 cmulf(float2 a, float2 b){
    return make_float2(a.x*b.x - a.y*b.y, a.x*b.y + a.y*b.x);
}
#define SW(i) ((i) ^ (((i)>>5)&31))
#define WB() __builtin_amdgcn_wave_barrier()

static constexpr double PI2   = 6.283185307179586;
static constexpr double KD    = PI2/0.00051;            // 2*pi/lambda
static constexpr double F0D   = 1.0/(2.0*(3.6/1024.0)); // 1/(2*PS)
static constexpr double FSTEP = 2.0*F0D/1023.0;
static constexpr double IL2D  = (1.0/0.00051)*(1.0/0.00051);
static constexpr double TPPID = PI2*8.74;               // 2*pi*T_PROP

// per-wave redundant W fill (768 entries; benign identical-value race, no barrier)
static __device__ __forceinline__ void load_W_wave(float2* W, const float2* Wg, int t){
    #pragma unroll
    for (int i = 0; i < 12; ++i){ int idx = t + 64*i; W[SW(idx)] = Wg[idx]; }
}

template<bool INV>
static __device__ __forceinline__ void bf4(const float2 a[4], float2 w1, float2 w2, float2 w3, float2 o[4]){
    if (INV){ w1.y = -w1.y; w2.y = -w2.y; w3.y = -w3.y; }
    float2 a1 = cmulf(a[1], w1), a2 = cmulf(a[2], w2), a3 = cmulf(a[3], w3);
    float2 t0 = make_float2(a[0].x+a2.x, a[0].y+a2.y);
    float2 t1 = make_float2(a[0].x-a2.x, a[0].y-a2.y);
    float2 t2 = make_float2(a1.x+a3.x, a1.y+a3.y);
    float2 t3 = make_float2(a1.x-a3.x, a1.y-a3.y);
    o[0] = make_float2(t0.x+t2.x, t0.y+t2.y);
    o[2] = make_float2(t0.x-t2.x, t0.y-t2.y);
    if (!INV){
        o[1] = make_float2(t1.x + t3.y, t1.y - t3.x);
        o[3] = make_float2(t1.x - t3.y, t1.y + t3.x);
    } else {
        o[1] = make_float2(t1.x - t3.y, t1.y + t3.x);
        o[3] = make_float2(t1.x + t3.y, t1.y - t3.x);
    }
}
template<bool INV>
static __device__ __forceinline__ void bf4nt(const float2 a[4], float2 o[4]){
    float2 t0 = make_float2(a[0].x+a[2].x, a[0].y+a[2].y);
    float2 t1 = make_float2(a[0].x-a[2].x, a[0].y-a[2].y);
    float2 t2 = make_float2(a[1].x+a[3].x, a[1].y+a[3].y);
    float2 t3 = make_float2(a[1].x-a[3].x, a[1].y-a[3].y);
    o[0] = make_float2(t0.x+t2.x, t0.y+t2.y);
    o[2] = make_float2(t0.x-t2.x, t0.y-t2.y);
    if (!INV){
        o[1] = make_float2(t1.x + t3.y, t1.y - t3.x);
        o[3] = make_float2(t1.x - t3.y, t1.y + t3.x);
    } else {
        o[1] = make_float2(t1.x - t3.y, t1.y + t3.x);
        o[3] = make_float2(t1.x + t3.y, t1.y - t3.x);
    }
}

// ===== radix-16 1024-pt Stockham, ONE WAVE per FFT, wave-private LDS slice =====
static __device__ __forceinline__ void r16_load(const float2* B, int t, float2 a[4][4]){
    #pragma unroll
    for (int k = 0; k < 4; ++k)
        #pragma unroll
        for (int q = 0; q < 4; ++q)
            a[k][q] = B[SW(t + 64*k + 256*q)];
}
template<bool INV>
static __device__ __forceinline__ void r16_s14(const float2 a[4][4], const float2* W, float2 z[4][4]){
    float2 y[4][4];
    #pragma unroll
    for (int k = 0; k < 4; ++k) bf4nt<INV>(a[k], y[k]);
    #pragma unroll
    for (int i = 0; i < 4; ++i){
        float2 b[4] = { y[0][i], y[1][i], y[2][i], y[3][i] };
        bf4<INV>(b, W[SW(64*i)], W[SW(128*i)], W[SW(192*i)], z[i]);
    }
}
static __device__ __forceinline__ void r16_st1(float2* B, int t, const float2 z[4][4]){
    #pragma unroll
    for (int i = 0; i < 4; ++i)
        #pragma unroll
        for (int d = 0; d < 4; ++d)
            B[SW(16*t + i + 4*d)] = z[i][d];
}
template<bool INV>
static __device__ __forceinline__ void r16_s16_64(const float2 a[4][4], const float2* W, int t, float2 z[4][4]){
    int mt = t & 15;
    float2 y[4][4];
    float2 w1 = W[SW(16*mt)], w2 = W[SW(32*mt)], w3 = W[SW(48*mt)];
    #pragma unroll
    for (int k = 0; k < 4; ++k) bf4<INV>(a[k], w1, w2, w3, y[k]);
    #pragma unroll
    for (int n = 0; n < 4; ++n){
        int m2 = mt + 16*n;
        float2 b[4] = { y[0][n], y[1][n], y[2][n], y[3][n] };
        bf4<INV>(b, W[SW(4*m2)], W[SW(8*m2)], W[SW(12*m2)], z[n]);
    }
}
static __device__ __forceinline__ void r16_st2(float2* B, int t, const float2 z[4][4]){
    int base = 256*(t>>4) + (t&15);
    #pragma unroll
    for (int n = 0; n < 4; ++n)
        #pragma unroll
        for (int d = 0; d < 4; ++d)
            B[SW(base + 16*n + 64*d)] = z[n][d];
}
template<bool INV>
static __device__ __forceinline__ void r16_s256(const float2 a[4][4], const float2* W, int t, float2 z[4][4]){
    #pragma unroll
    for (int k = 0; k < 4; ++k){
        int j = t + 64*k;
        bf4<INV>(a[k], W[SW(j)], W[SW(2*j)], W[SW(3*j)], z[k]);
    }
}
static __device__ __forceinline__ void r16_st3(float2* B, int t, const float2 z[4][4]){
    #pragma unroll
    for (int k = 0; k < 4; ++k)
        #pragma unroll
        for (int d = 0; d < 4; ++d)
            B[SW(t + 64*k + 256*d)] = z[k][d];
}
// input a[k][q] = element t+64k+256q; output z[k][d] = element t+64k+256d
template<bool INV>
static __device__ void r16_fft_regs(float2* B, const float2* W, int t, float2 a[4][4], float2 z[4][4]){
    float2 b[4][4];
    r16_s14<INV>(a, W, z);
    WB(); r16_st1(B, t, z); WB();
    r16_load(B, t, b); r16_s16_64<INV>(b, W, t, z);
    WB(); r16_st2(B, t, z); WB();
    r16_load(B, t, b); r16_s256<INV>(b, W, t, z);
}

static __device__ __forceinline__ float2 expi_from_double(double ph){
    double t = ph * (1.0/PI2);
    t -= floor(t);
    float th = (float)(t * PI2);
    float s, c; sincosf(th, &s, &c);
    return make_float2(c, s);
}

// exchange: write 4-row transposed chunks; caller did st3 + __syncthreads
static __device__ __forceinline__ void exch_write(const float2* buf, float2* dst,
        int tid, int r0, int jmax){
    #pragma unroll
    for (int cc = 0; cc < 4; ++cc){
        int j = tid + 256*cc;
        if (j < jmax){
            float2 v0 = buf[SW(j)];
            float2 v1 = buf[SSTR + SW(j)];
            float2 v2 = buf[2*SSTR + SW(j)];
            float2 v3 = buf[3*SSTR + SW(j)];
            float4* p = (float4*)(dst + (size_t)j*1024 + r0);
            p[0] = make_float4(v0.x, v0.y, v1.x, v1.y);
            p[1] = make_float4(v2.x, v2.y, v3.x, v3.y);
        }
    }
}

// ---- prep: lens phase+aperture (sign-packed), masked-tF half transpose, twiddles ----
__global__ __launch_bounds__(256) void k_prep(const float* __restrict__ rlist,
        const float* __restrict__ xpos, const float* __restrict__ ypos,
        const float* __restrict__ tF, const float* __restrict__ dm,
        float* __restrict__ phiA, float* __restrict__ TMv, float2* __restrict__ Wg){
    __shared__ float Tt[32][33];
    int b = blockIdx.x, tid = threadIdx.x;
    if (b < 4096){
        int idx = b*256 + tid;
        int r = idx >> 10, c = idx & 1023;
        float x = (float)(-1.8 + c*(3.6/1023.0));
        float y = (float)(-1.8 + r*(3.6/1023.0));
        const float ca2 = (float)(0.165*0.165);
        float Ts = 0.f; int any = 0;
        for (int l = 0; l < NLENS; ++l){
            float dx = x - xpos[l], dy = y - ypos[l];
            float d2 = dx*dx + dy*dy;
            if (d2 <= ca2){
                float rr = rlist[l];
                Ts += rr - sqrtf(fmaxf(rr*rr - d2, 1e-12f));
                any = 1;
            }
        }
        int ap = any && (x*x + y*y) <= 0.81f;
        float phi = (float)(KD*(1.515 - 1.0)) * Ts;
        phiA[idx] = ap ? phi : -1.0f;
    } else if (b < 5120){
        int tb = b - 4096;
        int bx = tb & 31, by = tb >> 5;
        int tx = tid & 31, ty = tid >> 5;   // 32 x 8
        #pragma unroll
        for (int j = 0; j < 4; ++j){
            int r = by*32 + ty + 8*j, c = bx*32 + tx;
            float tv = tF[(size_t)r*1024 + c];
            float mv = dm[(size_t)r*1024 + c];
            Tt[ty+8*j][tx] = (mv > 0.f) ? tv : -1.0f;
        }
        __syncthreads();
        #pragma unroll
        for (int j = 0; j < 4; ++j){
            int c = bx*32 + ty + 8*j, r = by*32 + tx;
            if (c <= 512) TMv[(size_t)c*1024 + r] = Tt[tx][ty+8*j];
        }
    } else {
        int t = (b-5120)*256 + tid;   // 3 blocks -> 768 entries
        float a = (float)((double)t * (-PI2/1024.0));
        float s, c; sincosf(a, &s, &c);
        Wg[t] = make_float2(c, s);
    }
}

// ---- P1 (x-FFT): gen U1 rows -> fwd FFT -> write transposed T[kc][row] ----
__global__ __launch_bounds__(256,4) void k_p1(const float* __restrict__ phiA,
        const float* __restrict__ defocus, float2* __restrict__ T,
        const float2* __restrict__ Wg, int zoff){
    __shared__ float2 buf[4*SSTR];
    __shared__ float2 W[768];
    int tid = threadIdx.x, zz = blockIdx.y;
    int w = tid >> 6, t = tid & 63;
    load_W_wave(W, Wg, t);
    int r0 = blockIdx.x*4, row = r0 + w;
    float2* B = buf + w*SSTR;
    float zf = defocus[zoff + zz];
    float y  = (float)(-1.8 + row*(3.6/1023.0));
    const float KF = (float)KD;
    const float* pha = phiA + ((size_t)row << 10);
    float2 a[4][4], z[4][4];
    #pragma unroll
    for (int k = 0; k < 4; ++k)
        #pragma unroll
        for (int q = 0; q < 4; ++q){
            int idx = t + 64*k + 256*q;
            float x = (float)(-1.8 + idx*(3.6/1023.0));
            float v = pha[idx];
            float2 uu = make_float2(0.f, 0.f);
            if (v >= 0.f){
                float qq = x*x + y*y;
                float phi_in = (KF*qq) / (2.0f*zf);
                uu = expi_from_double((double)(phi_in + v));
            }
            a[k][q] = uu;
        }
    r16_fft_regs<false>(B, W, t, a, z);
    WB(); r16_st3(B, t, z);
    __syncthreads();
    exch_write(buf, T + ((size_t)zz << 20), tid, r0, 1024);
}

// ---- P2 (y-FFT): read T[kc][*] coalesced, fwd FFT, *H(fly), inv FFT, write S[y][kc] ----
__global__ __launch_bounds__(256,4) void k_p2(const float2* __restrict__ T,
        float2* __restrict__ S, const float2* __restrict__ Wg){
    __shared__ float2 buf[4*SSTR];
    __shared__ float2 W[768];
    int tid = threadIdx.x, zz = blockIdx.y;
    int w = tid >> 6, t = tid & 63;
    load_W_wave(W, Wg, t);
    int c0 = blockIdx.x*4, kc = c0 + w;
    float2* B = buf + w*SSTR;
    const float2* Tr = T + ((size_t)zz << 20) + ((size_t)kc << 10);
    float2 a[4][4], z[4][4];
    #pragma unroll
    for (int k = 0; k < 4; ++k)
        #pragma unroll
        for (int q = 0; q < 4; ++q)
            a[k][q] = Tr[t + 64*k + 256*q];
    r16_fft_regs<false>(B, W, t, a, z);
    // H on the fly (column term wave-uniform)
    int cs = (kc + 512) & 1023;
    float fc  = (float)(-F0D + cs*FSTEP);
    float fc2 = __fmul_rn(fc, fc);
    const float il2f = (float)IL2D, pf = (float)TPPID;
    #pragma unroll
    for (int k = 0; k < 4; ++k)
        #pragma unroll
        for (int d = 0; d < 4; ++d){
            int j2 = t + 64*k + 256*d;
            int rs = (j2 + 512) & 1023;
            float fr  = (float)(-F0D + rs*FSTEP);
            float kz2 = __fsub_rn(__fsub_rn(il2f, fc2), __fmul_rn(fr, fr));
            float kzf = sqrtf(fmaxf(kz2, 0.f));
            float2 h  = expi_from_double((double)__fmul_rn(pf, kzf));
            z[k][d] = cmulf(z[k][d], h);
        }
    r16_fft_regs<true>(B, W, t, z, a);
    const float sc = 1.0f/1024.0f;
    #pragma unroll
    for (int k = 0; k < 4; ++k)
        #pragma unroll
        for (int d = 0; d < 4; ++d){ a[k][d].x *= sc; a[k][d].y *= sc; }
    WB(); r16_st3(B, t, a);
    __syncthreads();
    exch_write(buf, S + ((size_t)zz << 20), tid, c0, 1024);
}

// ---- P3: read S rows, inv x-FFT -> p=|u|^2, row sums, fwd x-FFT(p), write T2[kc2<=512][y] ----
__global__ __launch_bounds__(256,4) void k_p3(const float2* __restrict__ S,
        float2* __restrict__ T2, float* __restrict__ sumPartz, const float2* __restrict__ Wg){
    __shared__ float2 buf[4*SSTR];
    __shared__ float2 W[768];
    int tid = threadIdx.x, zz = blockIdx.y;
    int w = tid >> 6, t = tid & 63;
    load_W_wave(W, Wg, t);
    int y0 = blockIdx.x*4, y = y0 + w;
    float2* B = buf + w*SSTR;
    const float2* Srow = S + ((size_t)zz << 20) + ((size_t)y << 10);
    float2 a[4][4], z[4][4];
    #pragma unroll
    for (int k = 0; k < 4; ++k)
        #pragma unroll
        for (int q = 0; q < 4; ++q)
            a[k][q] = Srow[t + 64*k + 256*q];
    r16_fft_regs<true>(B, W, t, a, z);
    const float s2 = (1.0f/1024.0f)*(1.0f/1024.0f);
    float lsum = 0.f;
    #pragma unroll
    for (int k = 0; k < 4; ++k)
        #pragma unroll
        for (int d = 0; d < 4; ++d){
            float2 u = z[k][d];
            float p = (u.x*u.x + u.y*u.y) * s2;
            a[k][d] = make_float2(p, 0.f);
            lsum += p;
        }
    for (int o = 32; o > 0; o >>= 1) lsum += __shfl_down(lsum, o, 64);
    if (t == 0) sumPartz[zz*1024 + y] = lsum;
    WB();
    r16_fft_regs<false>(B, W, t, a, z);
    WB(); r16_st3(B, t, z);
    __syncthreads();
    exch_write(buf, T2 + (size_t)zz*PSTH, tid, y0, 513);
}

// ---- P4 (half): read T2[kc][*], fwd y-FFT, scale 1/sum, weighted diag, write ST[kc][kr] ----
__global__ __launch_bounds__(256,4) void k_p4(const float2* __restrict__ T2,
        float2* __restrict__ ST, const float* __restrict__ sumPartz,
        const float* __restrict__ TMv, float* __restrict__ dpartz,
        const float2* __restrict__ Wg){
    __shared__ float2 buf[4*SSTR];
    __shared__ float2 W[768];
    int tid = threadIdx.x, zz = blockIdx.y;
    int w = tid >> 6, t = tid & 63;
    int kc = blockIdx.x*4 + w;
    if (kc > 512) return;
    load_W_wave(W, Wg, t);
    float2* B = buf + w*SSTR;
    double sd = 0.0;
    for (int i = t; i < 1024; i += 64) sd += (double)sumPartz[zz*1024 + i];
    for (int o = 32; o > 0; o >>= 1) sd += __shfl_down(sd, o, 64);
    sd = __shfl(sd, 0, 64);
    float inv = (float)(1.0/sd);
    const float2* Tr = T2 + (size_t)zz*PSTH + ((size_t)kc << 10);
    float2 a[4][4], z[4][4];
    #pragma unroll
    for (int k = 0; k < 4; ++k)
        #pragma unroll
        for (int q = 0; q < 4; ++q)
            a[k][q] = Tr[t + 64*k + 256*q];
    r16_fft_regs<false>(B, W, t, a, z);
    const float* TMc = TMv + ((size_t)kc << 10);
    const float nrm = 1.0f/1048576.0f;
    float dacc = 0.f;
    float2* STr = ST + (size_t)zz*PSTH + ((size_t)kc << 10);
    #pragma unroll
    for (int k = 0; k < 4; ++k)
        #pragma unroll
        for (int d = 0; d < 4; ++d){
            float2 s = z[k][d]; s.x *= inv; s.y *= inv;
            float tmv = TMc[t + 64*k + 256*d];
            if (tmv >= 0.f){
                float dff = (s.x*s.x + s.y*s.y - tmv) * nrm;
                dacc += dff * dff;
            }
            STr[t + 64*k + 256*d] = s;
        }
    for (int o = 32; o > 0; o >>= 1) dacc += __shfl_down(dacc, o, 64);
    float wgt = (kc == 0 || kc == 512) ? 1.f : 2.f;
    if (t == 0) dpartz[zz*1024 + kc] = dacc * wgt;
}

static __device__ __forceinline__ void pair_of(int p, int& a, int& b){
    int i = 0, c = NZ-1;
    while (p >= c){ p -= c; ++i; --c; }
    a = i; b = i + 1 + p;
}

// ---- pairA: G rows from half-ST (mirror for kc>512), inv kr-FFT, write U[y][kc] ----
__global__ __launch_bounds__(256,4) void k_pairA(const float2* __restrict__ ST,
        float2* __restrict__ U, int ubase, const float2* __restrict__ Wg){
    __shared__ float2 buf[4*SSTR];
    __shared__ float2 W[768];
    int tid = threadIdx.x, ug = blockIdx.y;
    int w = tid >> 6, t = tid & 63;
    load_W_wave(W, Wg, t);
    int c0 = blockIdx.x*4, kc = c0 + w;
    float2* B = buf + w*SSTR;
    int u = ubase + ug;
    int pa = 2*u, pb = (2*u+1 < NPAIR) ? (2*u+1) : (NPAIR-1);
    int i1, i2, j1, j2;
    pair_of(pa, i1, i2); pair_of(pb, j1, j2);
    int mirror = (kc > 512);
    int kci = mirror ? (1024 - kc) : kc;
    const float2* P1 = ST + (size_t)i1*PSTH + ((size_t)kci << 10);
    const float2* Q1 = ST + (size_t)i2*PSTH + ((size_t)kci << 10);
    const float2* P2 = ST + (size_t)j1*PSTH + ((size_t)kci << 10);
    const float2* Q2 = ST + (size_t)j2*PSTH + ((size_t)kci << 10);
    if (mirror){
        const float2* tmp = P1; P1 = Q1; Q1 = tmp;
        tmp = P2; P2 = Q2; Q2 = tmp;
    }
    float2 a[4][4], z[4][4];
    #pragma unroll
    for (int k = 0; k < 4; ++k)
        #pragma unroll
        for (int q = 0; q < 4; ++q){
            int idx = t + 64*k + 256*q;
            int ix  = mirror ? ((1024 - idx) & 1023) : idx;
            float2 x1 = P1[ix], y1 = Q1[ix], x2 = P2[ix], y2 = Q2[ix];
            float2 g1 = make_float2(x1.x*y1.x + x1.y*y1.y, x1.x*y1.y - x1.y*y1.x);
            float2 g2 = make_float2(x2.x*y2.x + x2.y*y2.y, x2.x*y2.y - x2.y*y2.x);
            a[k][q] = make_float2(g1.x - g2.y, g1.y + g2.x);
        }
    r16_fft_regs<true>(B, W, t, a, z);
    const float sc = 1.0f/1024.0f;
    #pragma unroll
    for (int k = 0; k < 4; ++k)
        #pragma unroll
        for (int d = 0; d < 4; ++d){ z[k][d].x *= sc; z[k][d].y *= sc; }
    WB(); r16_st3(B, t, z);
    __syncthreads();
    exch_write(buf, U + ((size_t)ug << 20), tid, c0, 1024);
}

// ---- pairB: read U rows, inv x-FFT, |Re|,|Im|, per-wave (max, sumexp) partials ----
__global__ __launch_bounds__(256,4) void k_pairB(const float2* __restrict__ U,
        float2* __restrict__ lsePart, int ubase, const float2* __restrict__ Wg){
    __shared__ float2 buf[4*SSTR];
    __shared__ float2 W[768];
    int tid = threadIdx.x, ug = blockIdx.y;
    int w = tid >> 6, t = tid & 63;
    load_W_wave(W, Wg, t);
    int y = blockIdx.x*4 + w;
    float2* B = buf + w*SSTR;
    int u = ubase + ug;
    const float2* Urow = U + ((size_t)ug << 20) + ((size_t)y << 10);
    float2 a[4][4], z[4][4];
    #pragma unroll
    for (int k = 0; k < 4; ++k)
        #pragma unroll
        for (int q = 0; q < 4; ++q)
            a[k][q] = Urow[t + 64*k + 256*q];
    r16_fft_regs<true>(B, W, t, a, z);
    const float sc = 1.0f/1024.0f;
    float m1 = -1.f, m2 = -1.f;
    #pragma unroll
    for (int k = 0; k < 4; ++k)
        #pragma unroll
        for (int d = 0; d < 4; ++d){
            float c1 = fabsf(z[k][d].x)*sc, c2 = fabsf(z[k][d].y)*sc;
            z[k][d] = make_float2(c1, c2);
            m1 = fmaxf(m1, c1); m2 = fmaxf(m2, c2);
        }
    for (int o = 32; o > 0; o >>= 1){
        m1 = fmaxf(m1, __shfl_down(m1, o, 64));
        m2 = fmaxf(m2, __shfl_down(m2, o, 64));
    }
    float M1 = __shfl(m1, 0, 64), M2 = __shfl(m2, 0, 64);
    float s1 = 0.f, s2 = 0.f;
    #pragma unroll
    for (int k = 0; k < 4; ++k)
        #pragma unroll
        for (int d = 0; d < 4; ++d){
            s1 += expf((z[k][d].x - M1) * 100.0f);
            s2 += expf((z[k][d].y - M2) * 100.0f);
        }
    for (int o = 32; o > 0; o >>= 1){
        s1 += __shfl_down(s1, o, 64);
        s2 += __shfl_down(s2, o, 64);
    }
    if (t == 0){
        lsePart[(size_t)(2*u)*1024 + y] = make_float2(M1, s1);
        if (2*u+1 < NPAIR)
            lsePart[(size_t)(2*u+1)*1024 + y] = make_float2(M2, s2);
    }
}

// ---- final: 10 diag sums (513 partials) + 45 off (1024 partial LSEs) ----
__global__ __launch_bounds__(256) void k_final(const float* __restrict__ dpart,
        const float2* __restrict__ lsePart, float* __restrict__ out){
    __shared__ double dred[4];
    __shared__ float fred[4];
    int b = blockIdx.x, tid = threadIdx.x;
    if (b < NZ){
        double s = (double)dpart[b*1024 + tid] + (double)dpart[b*1024 + 256 + tid];
        if (tid == 0) s += (double)dpart[b*1024 + 512];
        for (int o = 32; o > 0; o >>= 1) s += __shfl_down(s, o, 64);
        if ((tid & 63) == 0) dred[tid >> 6] = s;
        __syncthreads();
        if (tid == 0) out[b] = (float)(dred[0]+dred[1]+dred[2]+dred[3]);
    } else {
        int p = b - NZ;
        const float2* lp = lsePart + (size_t)p*1024;
        float2 v[4]; float m = -1e30f;
        #pragma unroll
        for (int c = 0; c < 4; ++c){ v[c] = lp[tid + 256*c]; m = fmaxf(m, v[c].x); }
        for (int o = 32; o > 0; o >>= 1) m = fmaxf(m, __shfl_down(m, o, 64));
        if ((tid & 63) == 0) fred[tid >> 6] = m;
        __syncthreads();
        float M = fmaxf(fmaxf(fred[0], fred[1]), fmaxf(fred[2], fred[3]));
        double s = 0.0;
        #pragma unroll
        for (int c = 0; c < 4; ++c)
            s += (double)v[c].y * (double)expf((v[c].x - M)*100.0f);
        for (int o = 32; o > 0; o >>= 1) s += __shfl_down(s, o, 64);
        if ((tid & 63) == 0) dred[tid >> 6] = s;
        __syncthreads();
        if (tid == 0)
            out[NZ + p] = (float)(30.0*(double)M + 0.3*log(dred[0]+dred[1]+dred[2]+dred[3]));
    }
}

extern "C" void kernel_launch(void* const* d_in, const int* in_sizes, int n_in,
                              void* d_out, int out_size, void* d_ws, size_t ws_size,
                              hipStream_t stream){
    const float* rlist   = (const float*)d_in[0];
    const float* xpos    = (const float*)d_in[1];
    const float* ypos    = (const float*)d_in[2];
    const float* defocus = (const float*)d_in[3];
    const float* tF      = (const float*)d_in[4];
    const float* dmask   = (const float*)d_in[5];
    float* out = (float*)d_out;

    char* ws = (char*)d_ws;
    float2* ST   = (float2*)(ws);                    // 10 half planes: 42,024,960 B
    float2* Sbat = (float2*)(ws + 42024960);         // 5 full planes:  41,943,040 B
    float2* A    = (float2*)(ws + 83968000);         // 5 full planes:  41,943,040 B
    float*  phiA = (float*) (ws + 125911040);        // 4 MiB
    float*  TMv  = (float*) (ws + 130105344);        // 513*1024*4 = 2,101,248 B
    char*   tail = ws + 132206592;
    float*  sumPart = (float*) (tail);               // 40,960
    float*  dpart   = (float*) (tail + 40960);       // 40,960
    float2* lsePart = (float2*)(tail + 81920);       // 368,640
    float2* Wg      = (float2*)(tail + 450560);      // 6,144  (end: 132,663,296)

    k_prep<<<5123, 256, 0, stream>>>(rlist, xpos, ypos, tF, dmask, phiA, TMv, Wg);
    for (int bz = 0; bz < 2; ++bz){
        int zoff = bz*5;
        k_p1<<<dim3(256, 5), 256, 0, stream>>>(phiA, defocus, A, Wg, zoff);
        k_p2<<<dim3(256, 5), 256, 0, stream>>>(A, Sbat, Wg);
        k_p3<<<dim3(256, 5), 256, 0, stream>>>(Sbat, A, sumPart + zoff*1024, Wg);
        k_p4<<<dim3(129, 5), 256, 0, stream>>>(A, ST + (size_t)zoff*PSTH,
                sumPart + zoff*1024, TMv, dpart + zoff*1024, Wg);
    }
    for (int g = 0; g < NUNIT; g += UB){
        int cnt = (NUNIT - g < UB) ? (NUNIT - g) : UB;
        k_pairA<<<dim3(256, cnt), 256, 0, stream>>>(ST, (float2*)A, g, Wg);
        k_pairB<<<dim3(256, cnt), 256, 0, stream>>>((float2*)A, lsePart, g, Wg);
    }
    k_final<<<NZ + NPAIR, 256, 0, stream>>>(dpart, lsePart, out);
}